// Round 8
// baseline (73.904 us; speedup 1.0000x reference)
//
#include <hip/hip_runtime.h>
#include <math.h>

#define MLEN 4096
#define LOG2M 12
#define RANK 8
#define NSAMP 2048
#define VEC 8      // m-points per thread (strided by 256)
#define NS  4      // samples (n) per thread, reusing Hft loads
#define TWN 4032   // per-stage compact twiddles for stages 7..12

__device__ __forceinline__ float softplus_f(float x) {
    return (x > 20.0f) ? x : log1pf(expf(x));
}

// ---------------------------------------------------------------------------
// Kernel 1: full complex FFT of softplus(H) rows -> Hft in d_ws (256 KB).
// In-place DIT, 32 KB data LDS + 31.5 KB twiddle table (total 65024 B,
// safely under the 64 KiB static limit). Stages 1..6 use inline trig
// (<=32 distinct twiddles, broadcast); stages 7..12 read the table
// (per-stage compact layout -> <=4-way bank aliasing, near-free).
// ---------------------------------------------------------------------------
__global__ __launch_bounds__(1024) void fft_rows_kernel(const float* __restrict__ H,
                                                        float2* __restrict__ Hft) {
    __shared__ float2 buf[MLEN];     // 32768 B
    __shared__ float2 tw[TWN];       // 32256 B
    const int d = blockIdx.x;
    const float* row = H + d * MLEN;

    // bit-reversed global load (16 KB row, L2-absorbed), linear LDS write
    for (int i = threadIdx.x; i < MLEN; i += 1024) {
        int src = (int)(__brev((unsigned)i) >> (32 - LOG2M));
        buf[i] = make_float2(softplus_f(row[src]), 0.0f);
    }
    // twiddle table: entry g covers stage s (half=2^(s-1), s in 7..12),
    // base(s) = half - 64, w = exp(-i*pi*k/half)
    for (int g = threadIdx.x; g < TWN; g += 1024) {
        const int v    = g + 64;            // in [64, 4096)
        const int s0   = 31 - __clz(v);     // floor(log2(v)) in [6, 11]
        const int half = 1 << s0;
        const int k    = v - half;
        const float ang = -3.14159265358979323846f * (float)k / (float)half;
        tw[g] = make_float2(__cosf(ang), __sinf(ang));
    }
    __syncthreads();

    // stages 1..6: inline trig
    for (int s = 1; s <= 6; ++s) {
        const int half = 1 << (s - 1);
#pragma unroll 2
        for (int p = threadIdx.x; p < (MLEN >> 1); p += 1024) {
            const int k  = p & (half - 1);
            const int i0 = ((p >> (s - 1)) << s) + k;
            const int i1 = i0 + half;
            const float ang = -3.14159265358979323846f * (float)k / (float)half;
            const float cw = __cosf(ang);
            const float sw = __sinf(ang);
            float2 a = buf[i0];
            float2 b = buf[i1];
            float tr = b.x * cw - b.y * sw;
            float ti = b.x * sw + b.y * cw;
            buf[i0] = make_float2(a.x + tr, a.y + ti);
            buf[i1] = make_float2(a.x - tr, a.y - ti);
        }
        __syncthreads();
    }
    // stages 7..12: table twiddles
    for (int s = 7; s <= LOG2M; ++s) {
        const int half  = 1 << (s - 1);
        const int tbase = half - 64;
#pragma unroll 2
        for (int p = threadIdx.x; p < (MLEN >> 1); p += 1024) {
            const int k  = p & (half - 1);
            const int i0 = ((p >> (s - 1)) << s) + k;
            const int i1 = i0 + half;
            const float2 w = tw[tbase + k];
            float2 a = buf[i0];
            float2 b = buf[i1];
            float tr = b.x * w.x - b.y * w.y;
            float ti = b.x * w.y + b.y * w.x;
            buf[i0] = make_float2(a.x + tr, a.y + ti);
            buf[i1] = make_float2(a.x - tr, a.y - ti);
        }
        __syncthreads();
    }

    float2* outrow = Hft + d * MLEN;
    for (int i = threadIdx.x; i < MLEN; i += 1024) outrow[i] = buf[i];
}

// ---------------------------------------------------------------------------
// Kernel 2: V[n,m] = sum_d softplus(W[n,d]) * exp(-i*2pi*tau[n,d]*m/M) * Hft[d,m]
// Phase recurrence; step phasors (identical across all threads of a block's
// (n,d) set) hoisted to LDS. Base phasor: per-thread native sin/cos.
// NS=4 samples x VEC=8 m-points per thread; last-k rotation skipped.
// Grid: (MLEN/(256*VEC), NSAMP/NS) = (2, 512) blocks of 256.
// ---------------------------------------------------------------------------
template <int REAL_ONLY>
__global__ __launch_bounds__(256) void mix_kernel(const float* __restrict__ W,
                                                  const float* __restrict__ tau,
                                                  const float2* __restrict__ Hft,
                                                  float* __restrict__ out) {
    const int tid = threadIdx.x;
    const int m0  = blockIdx.x * (256 * VEC) + tid;
    const int n0  = blockIdx.y * NS;

    __shared__ float  s_spw[NS * RANK];
    __shared__ float  s_tau[NS * RANK];
    __shared__ float2 s_step[NS * RANK];    // exp(-i*pi/8 * tau), shared by all threads
    if (tid < NS * RANK) {
        const float t = tau[n0 * RANK + tid];
        s_spw[tid] = softplus_f(W[n0 * RANK + tid]);
        s_tau[tid] = t;
        const float a1 = -0.39269908169872415481f * t;   // -pi/8 * t
        s_step[tid] = make_float2(__cosf(a1), __sinf(a1));
    }
    __syncthreads();

    float ar[NS][VEC];
    float ai[NS][VEC];   // dead (DCE) in REAL_ONLY instantiation
#pragma unroll
    for (int j = 0; j < NS; ++j)
#pragma unroll
        for (int k = 0; k < VEC; ++k) { ar[j][k] = 0.0f; ai[j][k] = 0.0f; }

    const float th0f = -6.28318530717958647692f * ((float)m0 * (1.0f / (float)MLEN));

#pragma unroll
    for (int d = 0; d < RANK; ++d) {
        float cs[NS], sn[NS], dc[NS], ds[NS];
#pragma unroll
        for (int j = 0; j < NS; ++j) {
            const float t   = s_tau[j * RANK + d];
            const float spw = s_spw[j * RANK + d];
            const float a0  = th0f * t;
            cs[j] = spw * __cosf(a0);        // phasor pre-scaled by softplus(W)
            sn[j] = spw * __sinf(a0);
            const float2 st = s_step[j * RANK + d];
            dc[j] = st.x;
            ds[j] = st.y;
        }
        const float2* __restrict__ hrow = Hft + d * MLEN + m0;
        float2 hv[VEC];
#pragma unroll
        for (int k = 0; k < VEC; ++k) hv[k] = hrow[k * 256];
#pragma unroll
        for (int k = 0; k < VEC; ++k) {
#pragma unroll
            for (int j = 0; j < NS; ++j) {
                ar[j][k] += cs[j] * hv[k].x - sn[j] * hv[k].y;
                if (!REAL_ONLY) ai[j][k] += cs[j] * hv[k].y + sn[j] * hv[k].x;
                if (k < VEC - 1) {           // last rotation is dead
                    const float ncs = cs[j] * dc[j] - sn[j] * ds[j];
                    sn[j] = cs[j] * ds[j] + sn[j] * dc[j];
                    cs[j] = ncs;
                }
            }
        }
    }

#pragma unroll
    for (int j = 0; j < NS; ++j) {
#pragma unroll
        for (int k = 0; k < VEC; ++k) {
            const size_t idx = (size_t)(n0 + j) * MLEN + m0 + k * 256;
            if (REAL_ONLY) out[idx] = ar[j][k];
            else ((float2*)out)[idx] = make_float2(ar[j][k], ai[j][k]);
        }
    }
}

extern "C" void kernel_launch(void* const* d_in, const int* in_sizes, int n_in,
                              void* d_out, int out_size, void* d_ws, size_t ws_size,
                              hipStream_t stream) {
    const float* W   = (const float*)d_in[0];   // (N, R)
    const float* H   = (const float*)d_in[1];   // (R, M)
    const float* tau = (const float*)d_in[2];   // (N, R)
    float2* Hft = (float2*)d_ws;                // (R, M) complex, 256 KB scratch
    float* out  = (float*)d_out;

    fft_rows_kernel<<<RANK, 1024, 0, stream>>>(H, Hft);

    const long long NM = (long long)NSAMP * MLEN;
    dim3 grid(MLEN / (256 * VEC), NSAMP / NS);
    if ((long long)out_size >= 2 * NM) {
        mix_kernel<0><<<grid, 256, 0, stream>>>(W, tau, Hft, out);
    } else {
        mix_kernel<1><<<grid, 256, 0, stream>>>(W, tau, Hft, out);
    }
}

// Round 9
// 38.847 us; speedup vs baseline: 1.9024x; 1.9024x over previous
//
#include <hip/hip_runtime.h>
#include <math.h>

#define MLEN 4096
#define RANK 8
#define NSAMP 2048
#define VEC 8      // m-points per thread (strided by 256)
#define NS  4      // samples (n) per thread, reusing Hft loads

__device__ __forceinline__ float softplus_f(float x) {
    return (x > 20.0f) ? x : log1pf(expf(x));
}

// ---------------------------------------------------------------------------
// Kernel 1: full complex FFT of softplus(H) rows -> Hft in d_ws (256 KB).
// Radix-4 DIT (4096 = 4^6), in-place in 32 KB LDS, base-4 digit-reversed
// load, natural-order output. 1024 threads = 1 butterfly/thread/stage,
// 6 stages -> half the LDS traffic of radix-2. Twiddles inline: one native
// sin/cos pair per butterfly; w^2, w^3 by complex multiply.
// ---------------------------------------------------------------------------
__global__ __launch_bounds__(1024) void fft_rows_kernel(const float* __restrict__ H,
                                                        float2* __restrict__ Hft) {
    __shared__ float2 buf[MLEN];            // 32 KB
    const int d = blockIdx.x;
    const float* row = H + d * MLEN;

    // base-4 digit-reversed load: bit-reverse 12 bits, then swap bit-pairs
    for (int i = threadIdx.x; i < MLEN; i += 1024) {
        unsigned x = __brev((unsigned)i) >> 20;                       // 12-bit reversal
        unsigned src = ((x & 0x555u) << 1) | ((x & 0xAAAu) >> 1);     // digit reversal
        buf[i] = make_float2(softplus_f(row[src]), 0.0f);
    }
    __syncthreads();

    for (int s = 0; s < 6; ++s) {
        const int quarter = 1 << (2 * s);
        const int p  = threadIdx.x;                   // 1024 butterflies/stage
        const int k  = p & (quarter - 1);
        const int j  = p >> (2 * s);
        const int i0 = (j << (2 * s + 2)) + k;
        const int i1 = i0 + quarter;
        const int i2 = i1 + quarter;
        const int i3 = i2 + quarter;
        // w1 = exp(-2*pi*i*k/L), L = 4*quarter; w2 = w1^2; w3 = w1*w2
        const float ang = -6.28318530717958647692f * (float)k / (float)(quarter << 2);
        const float c1 = __cosf(ang), s1 = __sinf(ang);
        const float c2 = c1 * c1 - s1 * s1, s2 = 2.0f * c1 * s1;
        const float c3 = c1 * c2 - s1 * s2, s3 = c1 * s2 + s1 * c2;

        float2 a = buf[i0];
        float2 b = buf[i1];
        float2 c = buf[i2];
        float2 e = buf[i3];
        b = make_float2(b.x * c1 - b.y * s1, b.x * s1 + b.y * c1);
        c = make_float2(c.x * c2 - c.y * s2, c.x * s2 + c.y * c2);
        e = make_float2(e.x * c3 - e.y * s3, e.x * s3 + e.y * c3);

        const float2 t0 = make_float2(a.x + c.x, a.y + c.y);
        const float2 t1 = make_float2(a.x - c.x, a.y - c.y);
        const float2 t2 = make_float2(b.x + e.x, b.y + e.y);
        const float2 t3 = make_float2(b.y - e.y, e.x - b.x);   // -i*(b-e)

        // disjoint per-thread index sets -> no intra-stage hazard
        buf[i0] = make_float2(t0.x + t2.x, t0.y + t2.y);
        buf[i1] = make_float2(t1.x + t3.x, t1.y + t3.y);
        buf[i2] = make_float2(t0.x - t2.x, t0.y - t2.y);
        buf[i3] = make_float2(t1.x - t3.x, t1.y - t3.y);
        __syncthreads();
    }

    float2* outrow = Hft + d * MLEN;
    for (int i = threadIdx.x; i < MLEN; i += 1024) outrow[i] = buf[i];
}

// ---------------------------------------------------------------------------
// Kernel 2: V[n,m] = sum_d softplus(W[n,d]) * exp(-i*2pi*tau[n,d]*m/M) * Hft[d,m]
// Phase recurrence, NS=4 x VEC=8 per thread. d-loop NOT unrolled
// (#pragma unroll 1): prevents the compiler hoisting all 8 ranks' Hft load
// batches (round-8 lesson: that hit VGPR=256 -> 9.8% occupancy).
// __launch_bounds__(256,4) caps VGPRs at ~128 -> 4 blocks/CU exactly fills.
// ---------------------------------------------------------------------------
template <int REAL_ONLY>
__global__ __launch_bounds__(256, 4) void mix_kernel(const float* __restrict__ W,
                                                     const float* __restrict__ tau,
                                                     const float2* __restrict__ Hft,
                                                     float* __restrict__ out) {
    const int tid = threadIdx.x;
    const int m0  = blockIdx.x * (256 * VEC) + tid;
    const int n0  = blockIdx.y * NS;

    __shared__ float  s_spw[NS * RANK];
    __shared__ float  s_tau[NS * RANK];
    __shared__ float2 s_step[NS * RANK];    // exp(-i*pi/8 * tau), block-uniform
    if (tid < NS * RANK) {
        const float t = tau[n0 * RANK + tid];
        s_spw[tid] = softplus_f(W[n0 * RANK + tid]);
        s_tau[tid] = t;
        const float a1 = -0.39269908169872415481f * t;   // -2*pi*256/4096 * t
        s_step[tid] = make_float2(__cosf(a1), __sinf(a1));
    }
    __syncthreads();

    float ar[NS][VEC];
    float ai[NS][VEC];   // dead (DCE) in REAL_ONLY instantiation
#pragma unroll
    for (int j = 0; j < NS; ++j)
#pragma unroll
        for (int k = 0; k < VEC; ++k) { ar[j][k] = 0.0f; ai[j][k] = 0.0f; }

    const float th0f = -6.28318530717958647692f * ((float)m0 * (1.0f / (float)MLEN));

#pragma unroll 1
    for (int d = 0; d < RANK; ++d) {
        float cs[NS], sn[NS], dc[NS], ds[NS];
#pragma unroll
        for (int j = 0; j < NS; ++j) {
            const float t   = s_tau[j * RANK + d];
            const float spw = s_spw[j * RANK + d];
            const float a0  = th0f * t;
            cs[j] = spw * __cosf(a0);        // phasor pre-scaled by softplus(W)
            sn[j] = spw * __sinf(a0);
            const float2 st = s_step[j * RANK + d];
            dc[j] = st.x;
            ds[j] = st.y;
        }
        const float2* __restrict__ hrow = Hft + d * MLEN + m0;
        float2 hv[VEC];
#pragma unroll
        for (int k = 0; k < VEC; ++k) hv[k] = hrow[k * 256];
#pragma unroll
        for (int k = 0; k < VEC; ++k) {
#pragma unroll
            for (int j = 0; j < NS; ++j) {
                ar[j][k] += cs[j] * hv[k].x - sn[j] * hv[k].y;
                if (!REAL_ONLY) ai[j][k] += cs[j] * hv[k].y + sn[j] * hv[k].x;
                if (k < VEC - 1) {           // last rotation is dead
                    const float ncs = cs[j] * dc[j] - sn[j] * ds[j];
                    sn[j] = cs[j] * ds[j] + sn[j] * dc[j];
                    cs[j] = ncs;
                }
            }
        }
    }

#pragma unroll
    for (int j = 0; j < NS; ++j) {
#pragma unroll
        for (int k = 0; k < VEC; ++k) {
            const size_t idx = (size_t)(n0 + j) * MLEN + m0 + k * 256;
            if (REAL_ONLY) out[idx] = ar[j][k];
            else ((float2*)out)[idx] = make_float2(ar[j][k], ai[j][k]);
        }
    }
}

extern "C" void kernel_launch(void* const* d_in, const int* in_sizes, int n_in,
                              void* d_out, int out_size, void* d_ws, size_t ws_size,
                              hipStream_t stream) {
    const float* W   = (const float*)d_in[0];   // (N, R)
    const float* H   = (const float*)d_in[1];   // (R, M)
    const float* tau = (const float*)d_in[2];   // (N, R)
    float2* Hft = (float2*)d_ws;                // (R, M) complex, 256 KB scratch
    float* out  = (float*)d_out;

    fft_rows_kernel<<<RANK, 1024, 0, stream>>>(H, Hft);

    const long long NM = (long long)NSAMP * MLEN;
    dim3 grid(MLEN / (256 * VEC), NSAMP / NS);
    if ((long long)out_size >= 2 * NM) {
        mix_kernel<0><<<grid, 256, 0, stream>>>(W, tau, Hft, out);
    } else {
        mix_kernel<1><<<grid, 256, 0, stream>>>(W, tau, Hft, out);
    }
}

// Round 10
// 37.146 us; speedup vs baseline: 1.9896x; 1.0458x over previous
//
#include <hip/hip_runtime.h>
#include <math.h>

#define MLEN 4096
#define RANK 8
#define NSAMP 2048
#define VEC 4      // m-points per thread (strided by 256)
#define NS  4      // samples (n) per thread, reusing Hft loads

__device__ __forceinline__ float softplus_f(float x) {
    return (x > 20.0f) ? x : log1pf(expf(x));
}

// ---------------------------------------------------------------------------
// Kernel 1: full complex FFT of softplus(H) rows -> Hft in d_ws (256 KB).
// Radix-4 DIT (4096 = 4^6), in-place in 32 KB LDS, base-4 digit-reversed
// load, natural-order output. 1024 threads = 1 butterfly/thread/stage.
// (Proven correct in round 8/9; est 4-6 us.)
// ---------------------------------------------------------------------------
__global__ __launch_bounds__(1024) void fft_rows_kernel(const float* __restrict__ H,
                                                        float2* __restrict__ Hft) {
    __shared__ float2 buf[MLEN];            // 32 KB
    const int d = blockIdx.x;
    const float* row = H + d * MLEN;

    for (int i = threadIdx.x; i < MLEN; i += 1024) {
        unsigned x = __brev((unsigned)i) >> 20;                       // 12-bit reversal
        unsigned src = ((x & 0x555u) << 1) | ((x & 0xAAAu) >> 1);     // digit reversal
        buf[i] = make_float2(softplus_f(row[src]), 0.0f);
    }
    __syncthreads();

    for (int s = 0; s < 6; ++s) {
        const int quarter = 1 << (2 * s);
        const int p  = threadIdx.x;
        const int k  = p & (quarter - 1);
        const int j  = p >> (2 * s);
        const int i0 = (j << (2 * s + 2)) + k;
        const int i1 = i0 + quarter;
        const int i2 = i1 + quarter;
        const int i3 = i2 + quarter;
        const float ang = -6.28318530717958647692f * (float)k / (float)(quarter << 2);
        const float c1 = __cosf(ang), s1 = __sinf(ang);
        const float c2 = c1 * c1 - s1 * s1, s2 = 2.0f * c1 * s1;
        const float c3 = c1 * c2 - s1 * s2, s3 = c1 * s2 + s1 * c2;

        float2 a = buf[i0];
        float2 b = buf[i1];
        float2 c = buf[i2];
        float2 e = buf[i3];
        b = make_float2(b.x * c1 - b.y * s1, b.x * s1 + b.y * c1);
        c = make_float2(c.x * c2 - c.y * s2, c.x * s2 + c.y * c2);
        e = make_float2(e.x * c3 - e.y * s3, e.x * s3 + e.y * c3);

        const float2 t0 = make_float2(a.x + c.x, a.y + c.y);
        const float2 t1 = make_float2(a.x - c.x, a.y - c.y);
        const float2 t2 = make_float2(b.x + e.x, b.y + e.y);
        const float2 t3 = make_float2(b.y - e.y, e.x - b.x);   // -i*(b-e)

        buf[i0] = make_float2(t0.x + t2.x, t0.y + t2.y);
        buf[i1] = make_float2(t1.x + t3.x, t1.y + t3.y);
        buf[i2] = make_float2(t0.x - t2.x, t0.y - t2.y);
        buf[i3] = make_float2(t1.x - t3.x, t1.y - t3.y);
        __syncthreads();
    }

    float2* outrow = Hft + d * MLEN;
    for (int i = threadIdx.x; i < MLEN; i += 1024) outrow[i] = buf[i];
}

// ---------------------------------------------------------------------------
// Kernel 2: V[n,m] = sum_d softplus(W[n,d]) * exp(-i*2pi*tau[n,d]*m/M) * Hft[d,m]
// Phase recurrence. Round-9 lesson: the working set, not the unroll, was the
// disease (R7: VGPR=256/1 wave; R8: forced 128 cap -> spills). Shrink it:
// VEC=4 x NS=4 -> ar 16 + hv 8 + phasors 16 ~ 60-70 VGPR natural -> 8
// waves/SIMD with NO forced min-waves bound. d-loop kept at unroll 1.
// Grid: (MLEN/(256*VEC), NSAMP/NS) = (4, 512) = 2048 blocks of 256.
// ---------------------------------------------------------------------------
template <int REAL_ONLY>
__global__ __launch_bounds__(256) void mix_kernel(const float* __restrict__ W,
                                                  const float* __restrict__ tau,
                                                  const float2* __restrict__ Hft,
                                                  float* __restrict__ out) {
    const int tid = threadIdx.x;
    const int m0  = blockIdx.x * (256 * VEC) + tid;
    const int n0  = blockIdx.y * NS;

    __shared__ float  s_spw[NS * RANK];
    __shared__ float  s_tau[NS * RANK];
    __shared__ float2 s_step[NS * RANK];    // exp(-i*2pi*256/M * tau), block-uniform
    if (tid < NS * RANK) {
        const float t = tau[n0 * RANK + tid];
        s_spw[tid] = softplus_f(W[n0 * RANK + tid]);
        s_tau[tid] = t;
        const float a1 = -0.39269908169872415481f * t;   // -2*pi*256/4096 * t
        s_step[tid] = make_float2(__cosf(a1), __sinf(a1));
    }
    __syncthreads();

    float ar[NS][VEC];
    float ai[NS][VEC];   // dead (DCE) in REAL_ONLY instantiation
#pragma unroll
    for (int j = 0; j < NS; ++j)
#pragma unroll
        for (int k = 0; k < VEC; ++k) { ar[j][k] = 0.0f; ai[j][k] = 0.0f; }

    const float th0f = -6.28318530717958647692f * ((float)m0 * (1.0f / (float)MLEN));

#pragma unroll 1
    for (int d = 0; d < RANK; ++d) {
        float cs[NS], sn[NS], dc[NS], ds[NS];
#pragma unroll
        for (int j = 0; j < NS; ++j) {
            const float t   = s_tau[j * RANK + d];
            const float spw = s_spw[j * RANK + d];
            const float a0  = th0f * t;
            cs[j] = spw * __cosf(a0);        // phasor pre-scaled by softplus(W)
            sn[j] = spw * __sinf(a0);
            const float2 st = s_step[j * RANK + d];
            dc[j] = st.x;
            ds[j] = st.y;
        }
        const float2* __restrict__ hrow = Hft + d * MLEN + m0;
        float2 hv[VEC];
#pragma unroll
        for (int k = 0; k < VEC; ++k) hv[k] = hrow[k * 256];
#pragma unroll
        for (int k = 0; k < VEC; ++k) {
#pragma unroll
            for (int j = 0; j < NS; ++j) {
                ar[j][k] += cs[j] * hv[k].x - sn[j] * hv[k].y;
                if (!REAL_ONLY) ai[j][k] += cs[j] * hv[k].y + sn[j] * hv[k].x;
                if (k < VEC - 1) {           // last rotation is dead
                    const float ncs = cs[j] * dc[j] - sn[j] * ds[j];
                    sn[j] = cs[j] * ds[j] + sn[j] * dc[j];
                    cs[j] = ncs;
                }
            }
        }
    }

#pragma unroll
    for (int j = 0; j < NS; ++j) {
#pragma unroll
        for (int k = 0; k < VEC; ++k) {
            const size_t idx = (size_t)(n0 + j) * MLEN + m0 + k * 256;
            if (REAL_ONLY) out[idx] = ar[j][k];
            else ((float2*)out)[idx] = make_float2(ar[j][k], ai[j][k]);
        }
    }
}

extern "C" void kernel_launch(void* const* d_in, const int* in_sizes, int n_in,
                              void* d_out, int out_size, void* d_ws, size_t ws_size,
                              hipStream_t stream) {
    const float* W   = (const float*)d_in[0];   // (N, R)
    const float* H   = (const float*)d_in[1];   // (R, M)
    const float* tau = (const float*)d_in[2];   // (N, R)
    float2* Hft = (float2*)d_ws;                // (R, M) complex, 256 KB scratch
    float* out  = (float*)d_out;

    fft_rows_kernel<<<RANK, 1024, 0, stream>>>(H, Hft);

    const long long NM = (long long)NSAMP * MLEN;
    dim3 grid(MLEN / (256 * VEC), NSAMP / NS);
    if ((long long)out_size >= 2 * NM) {
        mix_kernel<0><<<grid, 256, 0, stream>>>(W, tau, Hft, out);
    } else {
        mix_kernel<1><<<grid, 256, 0, stream>>>(W, tau, Hft, out);
    }
}